// Round 9
// baseline (288.695 us; speedup 1.0000x reference)
//
#include <hip/hip_runtime.h>

// Problem constants (X, Y: (64, 128, 64) fp32)
#define AA   64
#define MM   128
#define DD   64
#define CSTR 132                 // inc row stride (words); 132%32=4 -> 2-way banks (free)
#define NXY  512                 // XY gram blocks (4096 pairs, 8/block: 1 b x 8 a)
#define NTRI 288                 // triangle blocks per symmetric gram (8 pairs/block)
#define NBLK (NXY + 2*NTRI)      // 1088
// ws layout: [0,4MB) frag regions {Xhi,Xlo,Yhi,Ylo} each 1MB; [4MB,..) partials.
#define REG_I4 65536             // int4 per 1MB region
#define PART_OFF (4u << 20)

typedef float f32x4 __attribute__((ext_vector_type(4)));
typedef short bf8_t __attribute__((ext_vector_type(8)));

template <int CTRL, int RM>
__device__ __forceinline__ float dpp0(float x) {
    return __int_as_float(
        __builtin_amdgcn_update_dpp(0, __float_as_int(x), CTRL, RM, 0xF, false));
}

__device__ __forceinline__ unsigned bf16_rne(float v) {
    unsigned u = __float_as_uint(v);
    return (u + 0x7FFFu + ((u >> 16) & 1u)) >> 16;
}
__device__ __forceinline__ float bf16_tof(unsigned h) {
    return __uint_as_float(h << 16);
}

// Fence before overwriting an inc buffer: lgkmcnt(0) guarantees all prior
// ds_reads returned (R5-verified scheme); sched_barrier stops reordering.
// Placed so the waited-on loads were already chain-consumed -> near-free.
__device__ __forceinline__ void lds_fence() {
    asm volatile("s_waitcnt lgkmcnt(0)" ::: "memory");
    __builtin_amdgcn_sched_barrier(0);
}

// ---------------------------------------------------------------------------
// prep: build hi/lo bf16 fragments of dX/dY once, in MFMA fragment order.
// (R3/R5/R7-verified version: row 127 clamped to 126; col-127 handled by the
// lane-63 mask in the scan. v7's zeroing experiment REVERTED.)
// ---------------------------------------------------------------------------
__global__ __launch_bounds__(256) void prep_frags(const float* __restrict__ X,
                                                  const float* __restrict__ Y,
                                                  int4* __restrict__ frag) {
    const int tid = threadIdx.x, lane = tid & 63, w = tid >> 6;
    const int W    = blockIdx.x * 4 + w;   // 0..1023
    const int inp  = W >> 9;               // 0: X, 1: Y
    const int p    = (W >> 3) & 63;
    const int tile = W & 7;
    const float* S = (inp ? Y : X) + p * (MM * DD);
    int i = tile * 16 + (lane & 15);
    if (i > 126) i = 126;
    const int d0 = (lane >> 4) << 3;

    int4* hi = frag + (inp * 2 + 0) * REG_I4;
    int4* lo = frag + (inp * 2 + 1) * REG_I4;
    const int base = p * 1024 + tile * 128 + lane;

    #pragma unroll
    for (int ks = 0; ks < 2; ++ks) {
        const float* r0 = S + i * DD + ks * 32 + d0;
        const float* r1 = r0 + DD;
        float4 a0 = *(const float4*)r0;
        float4 a1 = *(const float4*)(r0 + 4);
        float4 c0 = *(const float4*)r1;
        float4 c1 = *(const float4*)(r1 + 4);
        float v[8] = {c0.x - a0.x, c0.y - a0.y, c0.z - a0.z, c0.w - a0.w,
                      c1.x - a1.x, c1.y - a1.y, c1.z - a1.z, c1.w - a1.w};
        unsigned hs[8], ls[8];
        #pragma unroll
        for (int e = 0; e < 8; ++e) {
            hs[e] = bf16_rne(v[e]);
            ls[e] = bf16_rne(v[e] - bf16_tof(hs[e]));
        }
        int4 h, l;
        h.x = hs[0] | (hs[1] << 16); h.y = hs[2] | (hs[3] << 16);
        h.z = hs[4] | (hs[5] << 16); h.w = hs[6] | (hs[7] << 16);
        l.x = ls[0] | (ls[1] << 16); l.y = ls[2] | (ls[3] << 16);
        l.z = ls[4] | (ls[5] << 16); l.w = ls[6] | (ls[7] << 16);
        hi[base + ks * 64] = h;
        lo[base + ks * 64] = l;
    }
}

// ---------------------------------------------------------------------------
// Scan helpers -- R7-verified recurrence (v7's T-form REVERTED):
//   k0 = 1 + sr1(S_prev); k1 = 1 + S_prev - e1p
//   e0 = e0p + k0*s0 ; e1 = e1p + k1*s1 (s1 masked 0 at lane 63)
//   S  = incl_scan64(e0 + e1)
// Final K[127][127] = 1 + S_prev - e1p at lane 63. Two pairs interleaved.
// ---------------------------------------------------------------------------
template <int ROWS>
__device__ __forceinline__ void load_sv(const float* buf, int c2l, float2* sv) {
    #pragma unroll
    for (int r = 0; r < ROWS; ++r)
        sv[r] = *(const float2*)(buf + r * CSTR + c2l);
}

template <int ROWS>
__device__ __forceinline__ void chain2_sv(const float2* svP, const float2* svQ,
                                          int lane,
                                          float& S0, float& e00, float& e10,
                                          float& S1, float& e01, float& e11) {
    #pragma unroll
    for (int r = 0; r < ROWS; ++r) {
        float s0a = svP[r].x, s1a = (lane < 63) ? svP[r].y : 0.0f;
        float s0b = svQ[r].x, s1b = (lane < 63) ? svQ[r].y : 0.0f;
        float Spa = dpp0<0x138, 0xF>(S0);
        float Spb = dpp0<0x138, 0xF>(S1);
        float k0a = 1.0f + Spa, k1a = 1.0f + S0 - e10;
        float k0b = 1.0f + Spb, k1b = 1.0f + S1 - e11;
        float e0a = fmaf(k0a, s0a, e00), e1a = fmaf(k1a, s1a, e10);
        float e0b = fmaf(k0b, s0b, e01), e1b = fmaf(k1b, s1b, e11);
        float Sa = e0a + e1a;
        float Sb = e0b + e1b;
        Sa += dpp0<0x111, 0xF>(Sa);  Sb += dpp0<0x111, 0xF>(Sb);
        Sa += dpp0<0x112, 0xF>(Sa);  Sb += dpp0<0x112, 0xF>(Sb);
        Sa += dpp0<0x114, 0xF>(Sa);  Sb += dpp0<0x114, 0xF>(Sb);
        Sa += dpp0<0x118, 0xF>(Sa);  Sb += dpp0<0x118, 0xF>(Sb);
        Sa += dpp0<0x142, 0xA>(Sa);  Sb += dpp0<0x142, 0xA>(Sb);
        Sa += dpp0<0x143, 0xC>(Sa);  Sb += dpp0<0x143, 0xC>(Sb);
        S0 = Sa; e00 = e0a; e10 = e1a;
        S1 = Sb; e01 = e0b; e11 = e1b;
    }
}

// ---------------------------------------------------------------------------
// PDE kernel, 2 pairs per wave (8 per block, same b). Geometry = R7-verified.
// v8 = v6 internals + ONLY the 4-row quarter-buffer change (single variable):
// incS 8 x 4 x CSTR = 16.9 KB -> LDS 49.9 KB -> 3 blocks/CU, combined with
// 2 interleaved chains/wave. v7's N-prefetch regs removed: A frags are dead
// after MFMA_PASS, so next strip's globals load straight into A (-32 VGPR,
// peak live ~137 < 170 cap -> no spill, unlike v7's 415 MB scratch traffic).
// ---------------------------------------------------------------------------
__global__ __launch_bounds__(256, 3)
void sig_pde(const int4* __restrict__ frag, float* __restrict__ partials) {
    const int tid = threadIdx.x, lane = tid & 63, w = tid >> 6;
    const int gid = blockIdx.x;

    int b, a0, a1, ain, bin;
    float wgt0, wgt1;
    if (gid < NXY) {
        b = gid >> 3;
        int abase = (gid & 7) * 8;
        a0 = abase + 2 * w; a1 = a0 + 1;
        ain = 0; bin = 1;
        wgt0 = wgt1 = -2.0f / 4096.0f;
    } else {
        int t = gid - NXY;
        int inp = 0;
        if (t >= NTRI) { t -= NTRI; inp = 1; }
        int g = (int)((__builtin_sqrtf((float)(t + 1)) - 1.0f) * 0.5f);
        while (4 * (g + 1) * (g + 2) <= t) ++g;
        while (g > 0 && 4 * g * (g + 1) > t) --g;
        int r  = t - 4 * g * (g + 1);
        int bi = r / (g + 1);
        int c  = r - bi * (g + 1);
        b = 8 * g + bi;
        int abase = c * 8;
        a0 = abase + 2 * w; a1 = a0 + 1;
        ain = bin = inp;
        wgt0 = (a0 < b) ? (2.0f / 4096.0f) : ((a0 == b) ? (1.0f / 4096.0f) : 0.0f);
        wgt1 = (a1 < b) ? (2.0f / 4096.0f) : ((a1 == b) ? (1.0f / 4096.0f) : 0.0f);
    }

    __shared__ int4  Bh[1024], Bl[1024];     // 32 KB B fragments (hi/lo)
    __shared__ float incS[8][4 * CSTR];      // 16.9 KB: 2 x 4-row bufs per wave
    __shared__ float red8[8];

    {   // stage this block's B fragment set
        const int4* Bhg = frag + (bin * 2 + 0) * REG_I4 + b * 1024;
        const int4* Blg = frag + (bin * 2 + 1) * REG_I4 + b * 1024;
        #pragma unroll
        for (int c = 0; c < 4; ++c) {
            int idx = c * 256 + tid;
            Bh[idx] = Bhg[idx];
            Bl[idx] = Blg[idx];
        }
    }
    __syncthreads();

    const int4* Ahg0 = frag + (ain * 2 + 0) * REG_I4 + a0 * 1024;
    const int4* Alg0 = frag + (ain * 2 + 1) * REG_I4 + a0 * 1024;
    const int4* Ahg1 = frag + (ain * 2 + 0) * REG_I4 + a1 * 1024;
    const int4* Alg1 = frag + (ain * 2 + 1) * REG_I4 + a1 * 1024;

    int4 A0h[2], A0l[2], A1h[2], A1l[2];     // A frags (2 pairs); reloaded
                                             //   in-place each strip (no N)
    f32x4 acc[2][8];                          // 64 AGPR: both pairs' strips
    float S0 = 0.f, e00 = 0.f, e10 = 0.f;    // pair0 scan state
    float S1 = 0.f, e01 = 0.f, e11 = 0.f;    // pair1 scan state

    float* buf0 = &incS[2 * w + 0][0];
    float* buf1 = &incS[2 * w + 1][0];
    const int c2l = lane << 1;
    const int qw  = lane >> 4;               // lane quadrant = cluster owner
    const int c0w = lane & 15;

// 96 MFMA for both pairs; each B fragment read ONCE feeds both.
#define MFMA_PASS() do {                                                        \
    _Pragma("unroll")                                                           \
    for (int p_ = 0; p_ < 2; ++p_)                                              \
        _Pragma("unroll")                                                       \
        for (int t_ = 0; t_ < 8; ++t_) acc[p_][t_] = (f32x4){0.f,0.f,0.f,0.f};  \
    _Pragma("unroll")                                                           \
    for (int s_ = 0; s_ < 2; ++s_) {                                            \
        bf8_t ah0 = __builtin_bit_cast(bf8_t, A0h[s_]);                         \
        bf8_t al0 = __builtin_bit_cast(bf8_t, A0l[s_]);                         \
        bf8_t ah1 = __builtin_bit_cast(bf8_t, A1h[s_]);                         \
        bf8_t al1 = __builtin_bit_cast(bf8_t, A1l[s_]);                         \
        _Pragma("unroll")                                                       \
        for (int t_ = 0; t_ < 8; ++t_) {                                        \
            int fb = (t_ * 2 + s_) * 64 + lane;                                 \
            bf8_t bh = *(const bf8_t*)&Bh[fb];                                  \
            bf8_t bl = *(const bf8_t*)&Bl[fb];                                  \
            acc[0][t_] = __builtin_amdgcn_mfma_f32_16x16x32_bf16(ah0, bh, acc[0][t_], 0, 0, 0); \
            acc[1][t_] = __builtin_amdgcn_mfma_f32_16x16x32_bf16(ah1, bh, acc[1][t_], 0, 0, 0); \
            acc[0][t_] = __builtin_amdgcn_mfma_f32_16x16x32_bf16(ah0, bl, acc[0][t_], 0, 0, 0); \
            acc[1][t_] = __builtin_amdgcn_mfma_f32_16x16x32_bf16(ah1, bl, acc[1][t_], 0, 0, 0); \
            acc[0][t_] = __builtin_amdgcn_mfma_f32_16x16x32_bf16(al0, bh, acc[0][t_], 0, 0, 0); \
            acc[1][t_] = __builtin_amdgcn_mfma_f32_16x16x32_bf16(al1, bh, acc[1][t_], 0, 0, 0); \
        }                                                                       \
    }                                                                           \
} while (0)

// Quarter-strip store: lanes in quadrant q hold strip rows 4q..4q+3 in acc
// regs 0..3 -> buffer rows 0..3. MUST follow lds_fence (WAR, R5-scheme).
#define STORE_Q(p, q, buf) do {                                \
    if (qw == (q)) {                                           \
        float* pb = (buf) + c0w;                               \
        _Pragma("unroll")                                      \
        for (int t_ = 0; t_ < 8; ++t_) {                       \
            float* qq = pb + (t_ << 4);                        \
            qq[0]        = acc[p][t_][0];                      \
            qq[CSTR]     = acc[p][t_][1];                      \
            qq[2 * CSTR] = acc[p][t_][2];                      \
            qq[3 * CSTR] = acc[p][t_][3];                      \
        }                                                      \
    }                                                          \
} while (0)

// Direct in-place A reload (A dead after the preceding MFMA_PASS; compiler
// preserves the WAR dep, and the MFMA's operand reads complete ~60+ ops
// before these loads can write back).
#define LOAD_A(poff) do {                                      \
    int off = (poff) + lane;                                   \
    A0h[0] = Ahg0[off]; A0h[1] = Ahg0[off + 64];               \
    A0l[0] = Alg0[off]; A0l[1] = Alg0[off + 64];               \
    A1h[0] = Ahg1[off]; A1h[1] = Ahg1[off + 64];               \
    A1l[0] = Alg1[off]; A1l[1] = Alg1[off + 64];               \
} while (0)

    // prologue: strip 0 fragments + MFMAs
    LOAD_A(0);
    MFMA_PASS();                             // acc = inc strip 0, both pairs

    for (int s = 0; s < 8; ++s) {
        if (s < 7) LOAD_A((s + 1) * 128);    // next strip's A frags, in place

        // ---- clusters 0..2: 4 rows each, both pairs ---------------------
        #pragma unroll
        for (int q = 0; q < 3; ++q) {
            float2 sv0[4], sv1[4];
            lds_fence();                      // prior cluster's reads returned
            STORE_Q(0, q, buf0); load_sv<4>(buf0, c2l, sv0);
            STORE_Q(1, q, buf1); load_sv<4>(buf1, c2l, sv1);
            chain2_sv<4>(sv0, sv1, lane, S0, e00, e10, S1, e01, e11);
        }

        // ---- cluster 3: last rows; MFMA for strip s+1 after acc drained --
        lds_fence();
        STORE_Q(0, 3, buf0);
        STORE_Q(1, 3, buf1);
        if (s < 7) {
            float2 sv0[4], sv1[4];
            load_sv<4>(buf0, c2l, sv0);
            load_sv<4>(buf1, c2l, sv1);
            MFMA_PASS();                      // hides under chain + next fence
            chain2_sv<4>(sv0, sv1, lane, S0, e00, e10, S1, e01, e11);
        } else {
            float2 sv0[3], sv1[3];            // rows 124..126 (127 excluded)
            load_sv<3>(buf0, c2l, sv0);
            load_sv<3>(buf1, c2l, sv1);
            chain2_sv<3>(sv0, sv1, lane, S0, e00, e10, S1, e01, e11);
        }
    }

    if (lane == 63) {
        red8[2 * w + 0] = wgt0 * (1.0f + S0 - e10);  // K[127][127] pair0
        red8[2 * w + 1] = wgt1 * (1.0f + S1 - e11);  // K[127][127] pair1
    }
    __syncthreads();
    if (tid == 0) {
        float r = 0.f;
        #pragma unroll
        for (int i = 0; i < 8; ++i) r += red8[i];
        partials[gid] = r;
    }

#undef MFMA_PASS
#undef STORE_Q
#undef LOAD_A
}

// ---------------------------------------------------------------------------
// final: out[0] = sum(partials) + mean((X0-Y0)^2).
// ---------------------------------------------------------------------------
__global__ void final_sum(const float* __restrict__ X, const float* __restrict__ Y,
                          const float* __restrict__ partials, float* __restrict__ out) {
    __shared__ float red[4];
    int tid = threadIdx.x;                   // 256 threads
    float acc = 0.f;
    for (int e = tid; e < NBLK; e += 256) acc += partials[e];
    for (int e = tid; e < AA * DD; e += 256) {
        int aa = e >> 6, d = e & 63;
        float df = X[aa * (MM * DD) + d] - Y[aa * (MM * DD) + d];
        acc = fmaf(df * df, 1.0f / 4096.0f, acc);
    }
    #pragma unroll
    for (int off = 32; off > 0; off >>= 1) acc += __shfl_down(acc, off);
    if ((tid & 63) == 0) red[tid >> 6] = acc;
    __syncthreads();
    if (tid == 0) out[0] = red[0] + red[1] + red[2] + red[3];
}

extern "C" void kernel_launch(void* const* d_in, const int* in_sizes, int n_in,
                              void* d_out, int out_size, void* d_ws, size_t ws_size,
                              hipStream_t stream) {
    const float* X = (const float*)d_in[0];
    const float* Y = (const float*)d_in[1];
    float* out = (float*)d_out;
    int4*  frag = (int4*)d_ws;
    float* partials = (float*)((char*)d_ws + PART_OFF);

    hipLaunchKernelGGL(prep_frags, dim3(256), dim3(256), 0, stream, X, Y, frag);
    hipLaunchKernelGGL(sig_pde, dim3(NBLK), dim3(256), 0, stream, frag, partials);
    hipLaunchKernelGGL(final_sum, dim3(1), dim3(256), 0, stream, X, Y, partials, out);
}

// Round 10
// 186.544 us; speedup vs baseline: 1.5476x; 1.5476x over previous
//
#include <hip/hip_runtime.h>

// Problem constants (X, Y: (64, 128, 64) fp32)
#define AA   64
#define MM   128
#define DD   64
#define CSTR 132                 // inc row stride (words); 132%32=4 -> 2-way banks (free)
#define NXY  1024                // XY gram blocks (all 4096 pairs, 4/block)
#define NTRI 544                 // triangle blocks per symmetric gram (a<=b)
#define NBLK (NXY + 2*NTRI)      // 2112
// ws layout: [0..) NBLK float partials (frag regions eliminated in v9).

typedef float f32x4 __attribute__((ext_vector_type(4)));
typedef short bf8_t __attribute__((ext_vector_type(8)));

template <int CTRL, int RM>
__device__ __forceinline__ float dpp0(float x) {
    return __int_as_float(
        __builtin_amdgcn_update_dpp(0, __float_as_int(x), CTRL, RM, 0xF, false));
}

__device__ __forceinline__ unsigned bf16_rne(float v) {
    unsigned u = __float_as_uint(v);
    return (u + 0x7FFFu + ((u >> 16) & 1u)) >> 16;
}
__device__ __forceinline__ float bf16_tof(unsigned h) {
    return __uint_as_float(h << 16);
}

// Fence before overwriting an inc buffer: lgkmcnt(0) guarantees all prior
// ds_reads returned (R5-verified scheme); sched_barrier stops reordering.
__device__ __forceinline__ void lds_fence() {
    asm volatile("s_waitcnt lgkmcnt(0)" ::: "memory");
    __builtin_amdgcn_sched_barrier(0);
}

// Convert 8 fp32 deltas (rows r1-r0) to packed bf16 hi/lo frags.
// EXACT math of the verified prep_frags (R3/R5/R6).
__device__ __forceinline__ void cvt8(const float4& a0, const float4& a1,
                                     const float4& c0, const float4& c1,
                                     int4& h, int4& l) {
    float v[8] = {c0.x - a0.x, c0.y - a0.y, c0.z - a0.z, c0.w - a0.w,
                  c1.x - a1.x, c1.y - a1.y, c1.z - a1.z, c1.w - a1.w};
    unsigned hs[8], ls[8];
    #pragma unroll
    for (int e = 0; e < 8; ++e) {
        hs[e] = bf16_rne(v[e]);
        ls[e] = bf16_rne(v[e] - bf16_tof(hs[e]));
    }
    h.x = hs[0] | (hs[1] << 16); h.y = hs[2] | (hs[3] << 16);
    h.z = hs[4] | (hs[5] << 16); h.w = hs[6] | (hs[7] << 16);
    l.x = ls[0] | (ls[1] << 16); l.y = ls[2] | (ls[3] << 16);
    l.z = ls[4] | (ls[5] << 16); l.w = ls[6] | (ls[7] << 16);
}

// ---------------------------------------------------------------------------
// Scan helpers -- R5/R6-verified recurrence:
//   k0 = 1 + sr1(S_prev); k1 = 1 + S_prev - e1p
//   e0 = e0p + k0*s0 ; e1 = e1p + k1*s1 (s1 masked 0 at lane 63)
//   S  = incl_scan64(e0 + e1)
// Final K[127][127] = 1 + S_prev - e1p at lane 63 after the last row.
// ---------------------------------------------------------------------------
template <int ROWS>
__device__ __forceinline__ void load_sv(const float* incW, int c2l, float2* sv) {
    #pragma unroll
    for (int r = 0; r < ROWS; ++r)
        sv[r] = *(const float2*)(incW + r * CSTR + c2l);
}

template <int ROWS>
__device__ __forceinline__ void chain_sv(const float2* sv, int lane,
                                         float& Sv, float& e0p, float& e1p) {
    #pragma unroll
    for (int r = 0; r < ROWS; ++r) {
        float s0 = sv[r].x;
        float s1 = (lane < 63) ? sv[r].y : 0.0f;
        float Sp  = dpp0<0x138, 0xF>(Sv);            // S_prev(l-1), 0 at lane0
        float k0v = 1.0f + Sp;
        float k1v = 1.0f + Sv - e1p;
        float e0  = fmaf(k0v, s0, e0p);
        float e1  = fmaf(k1v, s1, e1p);
        float S   = e0 + e1;
        S += dpp0<0x111, 0xF>(S);                    // row_shr:1
        S += dpp0<0x112, 0xF>(S);                    // row_shr:2
        S += dpp0<0x114, 0xF>(S);                    // row_shr:4
        S += dpp0<0x118, 0xF>(S);                    // row_shr:8
        S += dpp0<0x142, 0xA>(S);                    // row_bcast:15
        S += dpp0<0x143, 0xC>(S);                    // row_bcast:31
        Sv = S; e0p = e0; e1p = e1;
    }
}

// ---------------------------------------------------------------------------
// PDE kernel (v9 = the verified v5 structure with prep FUSED in).
// gid < 1024: XY gram. Else triangle blocks for XX / YY (v5 geometry).
// B-frags: built in-block from raw Y/X into LDS (exact prep math).
// A-frags: raw float4 loads issued at strip top (same prefetch slot as v5),
// converted to bf16 hi/lo just before the MFMAs. prep_frags kernel deleted.
// sig_pde internals otherwise identical to the 92.3 us / absmax-0 v5.
// ---------------------------------------------------------------------------
__global__ __launch_bounds__(256, 3)
void sig_pde(const float* __restrict__ X, const float* __restrict__ Y,
             float* __restrict__ partials) {
    const int tid = threadIdx.x, lane = tid & 63, w = tid >> 6;
    const int gid = blockIdx.x;

    int a, b, ain, bin;
    float wgt;
    if (gid < NXY) {
        b = gid >> 4; a = ((gid & 15) << 2) | w;
        ain = 0; bin = 1;
        wgt = -2.0f / 4096.0f;
    } else {
        int t = gid - NXY;
        int inp = 0;
        if (t >= NTRI) { t -= NTRI; inp = 1; }
        int q = (int)((__builtin_sqrtf((float)(2 * t + 1)) - 1.0f) * 0.5f);
        while (2 * (q + 1) * (q + 2) <= t) ++q;
        while (q > 0 && 2 * q * (q + 1) > t) --q;
        int r  = t - 2 * q * (q + 1);
        int i  = r / (q + 1);
        int ag = r - i * (q + 1);
        b = 4 * q + i; a = 4 * ag + w;
        ain = bin = inp;
        wgt = (a < b) ? (2.0f / 4096.0f) : ((a == b) ? (1.0f / 4096.0f) : 0.0f);
    }

    __shared__ int4  Bh[1024], Bl[1024];     // 32 KB B fragments (hi/lo)
    __shared__ float incS[4][8 * CSTR];      // 16.9 KB per-wave 8-row buffers
    __shared__ float red4[4];

    // --- build this block's B fragment set from RAW input (prep fused) ----
    {
        const float* Sb = (bin ? Y : X) + b * (MM * DD);
        #pragma unroll
        for (int c = 0; c < 4; ++c) {
            int e    = c * 256 + tid;        // 0..1023 = tile*128 + ks*64 + lb
            int tile = e >> 7;
            int rest = e & 127;
            int ks   = rest >> 6;
            int lb   = rest & 63;
            int i    = tile * 16 + (lb & 15);
            if (i > 126) i = 126;
            const float* r0 = Sb + i * DD + ((lb >> 4) << 3) + ks * 32;
            float4 a0 = *(const float4*)r0;
            float4 a1 = *(const float4*)(r0 + 4);
            float4 c0 = *(const float4*)(r0 + DD);
            float4 c1 = *(const float4*)(r0 + DD + 4);
            int4 h, l;
            cvt8(a0, a1, c0, c1, h, l);
            Bh[e] = h;
            Bl[e] = l;
        }
    }
    __syncthreads();

    const float* Sa = (ain ? Y : X) + a * (MM * DD);
    const int d0a = (lane >> 4) << 3;

    int4 Ah[2], Al[2];                       // current strip A frags (hi/lo)
    float4 F[8];                             // raw prefetch for next strip
    f32x4 acc[8];
    float Sv = 0.0f, e0p = 0.0f, e1p = 0.0f; // scan state

    float* incW = &incS[w][0];
    const int c2l = lane << 1;
    const int r0w = (lane >> 4) << 2, c0w = lane & 15;

// Raw A loads for strip sidx: rows i,i+1 at dims d0a(+32), 8 float4 total.
#define LOADRAW(sidx) do {                                     \
    int i_ = (sidx) * 16 + (lane & 15);                        \
    if (i_ > 126) i_ = 126;                                    \
    const float* p0 = Sa + i_ * DD + d0a;                      \
    F[0] = *(const float4*)p0;                                 \
    F[1] = *(const float4*)(p0 + 4);                           \
    F[2] = *(const float4*)(p0 + DD);                          \
    F[3] = *(const float4*)(p0 + DD + 4);                      \
    F[4] = *(const float4*)(p0 + 32);                          \
    F[5] = *(const float4*)(p0 + 36);                          \
    F[6] = *(const float4*)(p0 + DD + 32);                     \
    F[7] = *(const float4*)(p0 + DD + 36);                     \
} while (0)

#define CONV_A() do {                                          \
    cvt8(F[0], F[1], F[2], F[3], Ah[0], Al[0]);                \
    cvt8(F[4], F[5], F[6], F[7], Ah[1], Al[1]);                \
} while (0)

// 48 MFMA on the current strip (hi*hi + hi*lo + lo*hi), acc[8] = 32 AGPR.
#define MFMA_STRIP() do {                                                       \
    _Pragma("unroll")                                                           \
    for (int t_ = 0; t_ < 8; ++t_) acc[t_] = (f32x4){0.f, 0.f, 0.f, 0.f};       \
    _Pragma("unroll")                                                           \
    for (int s_ = 0; s_ < 2; ++s_) {                                            \
        bf8_t ah = __builtin_bit_cast(bf8_t, Ah[s_]);                           \
        bf8_t al = __builtin_bit_cast(bf8_t, Al[s_]);                           \
        _Pragma("unroll")                                                       \
        for (int t_ = 0; t_ < 8; ++t_) {                                        \
            int fb = (t_ * 2 + s_) * 64 + lane;                                 \
            bf8_t bh = *(const bf8_t*)&Bh[fb];                                  \
            bf8_t bl = *(const bf8_t*)&Bl[fb];                                  \
            acc[t_] = __builtin_amdgcn_mfma_f32_16x16x32_bf16(ah, bh, acc[t_], 0, 0, 0); \
            acc[t_] = __builtin_amdgcn_mfma_f32_16x16x32_bf16(ah, bl, acc[t_], 0, 0, 0); \
            acc[t_] = __builtin_amdgcn_mfma_f32_16x16x32_bf16(al, bh, acc[t_], 0, 0, 0); \
        }                                                                       \
    }                                                                           \
} while (0)

// Half-strip store: half 0 -> strip rows 0..7 (lanes r0w<8), half 1 ->
// strip rows 8..15 (lanes r0w>=8), both landing on buffer rows 0..7.
// MUST be preceded by lds_fence() (prior reads of the buffer returned).
#define STORE_H(half) do {                                     \
    if ((r0w & 8) == ((half) << 3)) {                          \
        float* pb = incW + (r0w & 7) * CSTR + c0w;             \
        _Pragma("unroll")                                      \
        for (int t_ = 0; t_ < 8; ++t_) {                       \
            float* q = pb + (t_ << 4);                         \
            q[0]        = acc[t_][0];                          \
            q[CSTR]     = acc[t_][1];                          \
            q[2 * CSTR] = acc[t_][2];                          \
            q[3 * CSTR] = acc[t_][3];                          \
        }                                                      \
    }                                                          \
} while (0)

    // prologue: strip 0 fragments + MFMAs
    LOADRAW(0);
    CONV_A();
    MFMA_STRIP();                            // acc = inc strip 0

    for (int s = 0; s < 8; ++s) {
        if (s < 7) LOADRAW(s + 1);           // raw prefetch (same slot as v5)

        // transpose acc -> regs via fenced 8-row buffer (R5-verified scheme)
        float2 svA[8];
        lds_fence(); STORE_H(0);
        load_sv<8>(incW, c2l, svA);
        lds_fence(); STORE_H(1);

        if (s < 7) {
            float2 svB[8];
            load_sv<8>(incW, c2l, svB);
            chain_sv<8>(svA, lane, Sv, e0p, e1p);
            CONV_A();                        // raw -> bf16 frags (hidden VALU)
            MFMA_STRIP();                    // next strip; hides under chains
            chain_sv<8>(svB, lane, Sv, e0p, e1p);
        } else {
            float2 svB[7];                   // last strip: 8 + 7 rows
            load_sv<7>(incW, c2l, svB);
            chain_sv<8>(svA, lane, Sv, e0p, e1p);
            chain_sv<7>(svB, lane, Sv, e0p, e1p);
        }
    }

    if (lane == 63) red4[w] = wgt * (1.0f + Sv - e1p);  // weighted K[127][127]
    __syncthreads();
    if (tid == 0)
        partials[gid] = red4[0] + red4[1] + red4[2] + red4[3];

#undef LOADRAW
#undef CONV_A
#undef MFMA_STRIP
#undef STORE_H
}

// ---------------------------------------------------------------------------
// final: out[0] = sum(partials) + mean((X0-Y0)^2). Folds the msq term with
// the 1/4096 mean weight so one reduction suffices.
// ---------------------------------------------------------------------------
__global__ void final_sum(const float* __restrict__ X, const float* __restrict__ Y,
                          const float* __restrict__ partials, float* __restrict__ out) {
    __shared__ float red[4];
    int tid = threadIdx.x;                   // 256 threads
    float acc = 0.f;
    for (int e = tid; e < NBLK; e += 256) acc += partials[e];
    for (int e = tid; e < AA * DD; e += 256) {
        int aa = e >> 6, d = e & 63;
        float df = X[aa * (MM * DD) + d] - Y[aa * (MM * DD) + d];
        acc = fmaf(df * df, 1.0f / 4096.0f, acc);
    }
    #pragma unroll
    for (int off = 32; off > 0; off >>= 1) acc += __shfl_down(acc, off);
    if ((tid & 63) == 0) red[tid >> 6] = acc;
    __syncthreads();
    if (tid == 0) out[0] = red[0] + red[1] + red[2] + red[3];
}

extern "C" void kernel_launch(void* const* d_in, const int* in_sizes, int n_in,
                              void* d_out, int out_size, void* d_ws, size_t ws_size,
                              hipStream_t stream) {
    const float* X = (const float*)d_in[0];
    const float* Y = (const float*)d_in[1];
    float* out = (float*)d_out;
    float* partials = (float*)d_ws;

    hipLaunchKernelGGL(sig_pde, dim3(NBLK), dim3(256), 0, stream, X, Y, partials);
    hipLaunchKernelGGL(final_sum, dim3(1), dim3(256), 0, stream, X, Y, partials, out);
}

// Round 11
// 149.296 us; speedup vs baseline: 1.9337x; 1.2495x over previous
//
#include <hip/hip_runtime.h>

// Problem constants (X, Y: (64, 128, 64) fp32)
#define AA   64
#define MM   128
#define DD   64
#define CSTR 132                 // inc row stride (words); 132%32=4 -> 2-way banks (free)
#define NXY  512                 // XY gram blocks (4096 pairs, 8/block: 1 b x 8 a)
#define NTRI 288                 // triangle blocks per symmetric gram (8 pairs/block)
#define NBLK (NXY + 2*NTRI)      // 1088
// ws layout: [0,4MB) frag regions {Xhi,Xlo,Yhi,Ylo} each 1MB; [4MB,..) partials.
#define REG_I4 65536             // int4 per 1MB region
#define PART_OFF (4u << 20)

typedef float f32x4 __attribute__((ext_vector_type(4)));
typedef short bf8_t __attribute__((ext_vector_type(8)));

template <int CTRL, int RM>
__device__ __forceinline__ float dpp0(float x) {
    return __int_as_float(
        __builtin_amdgcn_update_dpp(0, __float_as_int(x), CTRL, RM, 0xF, false));
}

__device__ __forceinline__ unsigned bf16_rne(float v) {
    unsigned u = __float_as_uint(v);
    return (u + 0x7FFFu + ((u >> 16) & 1u)) >> 16;
}
__device__ __forceinline__ float bf16_tof(unsigned h) {
    return __uint_as_float(h << 16);
}

// Fence before overwriting an inc buffer: lgkmcnt(0) guarantees all prior
// ds_reads returned (R5-verified scheme); sched_barrier stops reordering.
__device__ __forceinline__ void lds_fence() {
    asm volatile("s_waitcnt lgkmcnt(0)" ::: "memory");
    __builtin_amdgcn_sched_barrier(0);
}

// ---------------------------------------------------------------------------
// prep: build hi/lo bf16 fragments of dX/dY once, in MFMA fragment order.
// (R3/R5/R6-verified version: row 127 clamped; col 127 masked in the scan.)
// ---------------------------------------------------------------------------
__global__ __launch_bounds__(256) void prep_frags(const float* __restrict__ X,
                                                  const float* __restrict__ Y,
                                                  int4* __restrict__ frag) {
    const int tid = threadIdx.x, lane = tid & 63, w = tid >> 6;
    const int W    = blockIdx.x * 4 + w;   // 0..1023
    const int inp  = W >> 9;               // 0: X, 1: Y
    const int p    = (W >> 3) & 63;
    const int tile = W & 7;
    const float* S = (inp ? Y : X) + p * (MM * DD);
    int i = tile * 16 + (lane & 15);
    if (i > 126) i = 126;
    const int d0 = (lane >> 4) << 3;

    int4* hi = frag + (inp * 2 + 0) * REG_I4;
    int4* lo = frag + (inp * 2 + 1) * REG_I4;
    const int base = p * 1024 + tile * 128 + lane;

    #pragma unroll
    for (int ks = 0; ks < 2; ++ks) {
        const float* r0 = S + i * DD + ks * 32 + d0;
        const float* r1 = r0 + DD;
        float4 a0 = *(const float4*)r0;
        float4 a1 = *(const float4*)(r0 + 4);
        float4 c0 = *(const float4*)r1;
        float4 c1 = *(const float4*)(r1 + 4);
        float v[8] = {c0.x - a0.x, c0.y - a0.y, c0.z - a0.z, c0.w - a0.w,
                      c1.x - a1.x, c1.y - a1.y, c1.z - a1.z, c1.w - a1.w};
        unsigned hs[8], ls[8];
        #pragma unroll
        for (int e = 0; e < 8; ++e) {
            hs[e] = bf16_rne(v[e]);
            ls[e] = bf16_rne(v[e] - bf16_tof(hs[e]));
        }
        int4 h, l;
        h.x = hs[0] | (hs[1] << 16); h.y = hs[2] | (hs[3] << 16);
        h.z = hs[4] | (hs[5] << 16); h.w = hs[6] | (hs[7] << 16);
        l.x = ls[0] | (ls[1] << 16); l.y = ls[2] | (ls[3] << 16);
        l.z = ls[4] | (ls[5] << 16); l.w = ls[6] | (ls[7] << 16);
        hi[base + ks * 64] = h;
        lo[base + ks * 64] = l;
    }
}

// ---------------------------------------------------------------------------
// v10 scan: half-wave-split, 4 cols/lane, 2 pairs per ONE chain pass.
// Lanes 0-31 own pair0 cols 4lq..4lq+3; lanes 32-63 own pair1 (lq = lane&31).
// Per-row recurrence (generalization of the R5-verified 2-col form):
//   Sp  = wf_sr1(Sv), forced 0 at lq==0 (group boundary)
//   k0 = 1+Sp;  k1 = 1+Sv-(e1p+e2p+e3p);  k2 = 1+Sv-(e2p+e3p);  k3 = 1+Sv-e3p
//   e_c = e_cp + k_c*s_c   (s3 masked 0 at lq==31: col 127)
//   Sv  = incl_scan32(e0+e1+e2+e3)   [row_shr 1,2,4,8 + row_bcast:15 RM 0xA;
//                                     row_bcast:31 DROPPED -> halves stay
//                                     independent]
// Final K[127][127] = 1 + Sv - e3p at lq==31 (e3p stays 0 there).
// ---------------------------------------------------------------------------
template <int ROWS>
__device__ __forceinline__ void load4(const float* buf, int c4, float4* sv) {
    #pragma unroll
    for (int r = 0; r < ROWS; ++r)
        sv[r] = *(const float4*)(buf + r * CSTR + c4);
}

template <int ROWS>
__device__ __forceinline__ void chain4(const float4* sv, bool lq0, bool lq31,
                                       float& Sv, float& e0p, float& e1p,
                                       float& e2p, float& e3p) {
    #pragma unroll
    for (int r = 0; r < ROWS; ++r) {
        float s0 = sv[r].x, s1 = sv[r].y, s2 = sv[r].z;
        float s3 = lq31 ? 0.0f : sv[r].w;            // col 127 mask
        float Sp = dpp0<0x138, 0xF>(Sv);             // wf_sr1
        Sp = lq0 ? 0.0f : Sp;                        // 32-group boundary
        float t23 = e2p + e3p;                       // off critical path
        float k0 = 1.0f + Sp;
        float k1 = 1.0f + (Sv - (e1p + t23));
        float k2 = 1.0f + (Sv - t23);
        float k3 = 1.0f + (Sv - e3p);
        float e0 = fmaf(k0, s0, e0p);
        float e1 = fmaf(k1, s1, e1p);
        float e2 = fmaf(k2, s2, e2p);
        float e3 = fmaf(k3, s3, e3p);
        float E = (e0 + e1) + (e2 + e3);
        E += dpp0<0x111, 0xF>(E);                    // row_shr:1
        E += dpp0<0x112, 0xF>(E);                    // row_shr:2
        E += dpp0<0x114, 0xF>(E);                    // row_shr:4
        E += dpp0<0x118, 0xF>(E);                    // row_shr:8
        E += dpp0<0x142, 0xA>(E);                    // row_bcast:15 (rows 1,3)
        Sv = E;
        e0p = e0; e1p = e1; e2p = e2; e3p = e3;
    }
}

// ---------------------------------------------------------------------------
// PDE kernel, 2 pairs per wave (8 per block, same b). v6 geometry + MFMA +
// store + fence structure (R7-verified, absmax 0); ONLY the scan is replaced
// by the half-wave-split chain4 (one chain pass serves both pairs -> per-pair
// chain issue halves; wave count already halved vs v5).
// ---------------------------------------------------------------------------
__global__ __launch_bounds__(256, 2)
void sig_pde(const int4* __restrict__ frag, float* __restrict__ partials) {
    const int tid = threadIdx.x, lane = tid & 63, w = tid >> 6;
    const int gid = blockIdx.x;

    int b, a0, a1, ain, bin;
    float wgt0, wgt1;
    if (gid < NXY) {
        b = gid >> 3;
        int abase = (gid & 7) * 8;
        a0 = abase + 2 * w; a1 = a0 + 1;
        ain = 0; bin = 1;
        wgt0 = wgt1 = -2.0f / 4096.0f;
    } else {
        int t = gid - NXY;
        int inp = 0;
        if (t >= NTRI) { t -= NTRI; inp = 1; }
        int g = (int)((__builtin_sqrtf((float)(t + 1)) - 1.0f) * 0.5f);
        while (4 * (g + 1) * (g + 2) <= t) ++g;
        while (g > 0 && 4 * g * (g + 1) > t) --g;
        int r  = t - 4 * g * (g + 1);
        int bi = r / (g + 1);
        int c  = r - bi * (g + 1);
        b = 8 * g + bi;
        int abase = c * 8;
        a0 = abase + 2 * w; a1 = a0 + 1;
        ain = bin = inp;
        wgt0 = (a0 < b) ? (2.0f / 4096.0f) : ((a0 == b) ? (1.0f / 4096.0f) : 0.0f);
        wgt1 = (a1 < b) ? (2.0f / 4096.0f) : ((a1 == b) ? (1.0f / 4096.0f) : 0.0f);
    }

    __shared__ int4  Bh[1024], Bl[1024];     // 32 KB B fragments (hi/lo)
    __shared__ float incS[8][8 * CSTR];      // 33.8 KB: 2 x 8-row bufs per wave
    __shared__ float red8[8];

    {   // stage this block's B fragment set
        const int4* Bhg = frag + (bin * 2 + 0) * REG_I4 + b * 1024;
        const int4* Blg = frag + (bin * 2 + 1) * REG_I4 + b * 1024;
        #pragma unroll
        for (int c = 0; c < 4; ++c) {
            int idx = c * 256 + tid;
            Bh[idx] = Bhg[idx];
            Bl[idx] = Blg[idx];
        }
    }
    __syncthreads();

    const int4* Ahg0 = frag + (ain * 2 + 0) * REG_I4 + a0 * 1024;
    const int4* Alg0 = frag + (ain * 2 + 1) * REG_I4 + a0 * 1024;
    const int4* Ahg1 = frag + (ain * 2 + 0) * REG_I4 + a1 * 1024;
    const int4* Alg1 = frag + (ain * 2 + 1) * REG_I4 + a1 * 1024;

    int4 A0h[2], A0l[2], A1h[2], A1l[2];     // current strip A frags (2 pairs)
    int4 N0h[2], N0l[2], N1h[2], N1l[2];     // prefetched next strip (v6 style)
    f32x4 acc[2][8];                          // 64 AGPR: both pairs' strips
    float Sv = 0.f, e0p = 0.f, e1p = 0.f, e2p = 0.f, e3p = 0.f;

    float* buf0 = &incS[2 * w + 0][0];
    float* buf1 = &incS[2 * w + 1][0];
    const float* myBuf = (lane < 32) ? buf0 : buf1;  // scan-side pair split
    const int lq  = lane & 31;
    const int c4  = lq << 2;
    const bool lq0 = (lq == 0), lq31 = (lq == 31);
    const int r0w = (lane >> 4) << 2, c0w = lane & 15;

// 96 MFMA for both pairs; each B fragment read ONCE feeds both.
#define MFMA_PASS() do {                                                        \
    _Pragma("unroll")                                                           \
    for (int p_ = 0; p_ < 2; ++p_)                                              \
        _Pragma("unroll")                                                       \
        for (int t_ = 0; t_ < 8; ++t_) acc[p_][t_] = (f32x4){0.f,0.f,0.f,0.f};  \
    _Pragma("unroll")                                                           \
    for (int s_ = 0; s_ < 2; ++s_) {                                            \
        bf8_t ah0 = __builtin_bit_cast(bf8_t, A0h[s_]);                         \
        bf8_t al0 = __builtin_bit_cast(bf8_t, A0l[s_]);                         \
        bf8_t ah1 = __builtin_bit_cast(bf8_t, A1h[s_]);                         \
        bf8_t al1 = __builtin_bit_cast(bf8_t, A1l[s_]);                         \
        _Pragma("unroll")                                                       \
        for (int t_ = 0; t_ < 8; ++t_) {                                        \
            int fb = (t_ * 2 + s_) * 64 + lane;                                 \
            bf8_t bh = *(const bf8_t*)&Bh[fb];                                  \
            bf8_t bl = *(const bf8_t*)&Bl[fb];                                  \
            acc[0][t_] = __builtin_amdgcn_mfma_f32_16x16x32_bf16(ah0, bh, acc[0][t_], 0, 0, 0); \
            acc[1][t_] = __builtin_amdgcn_mfma_f32_16x16x32_bf16(ah1, bh, acc[1][t_], 0, 0, 0); \
            acc[0][t_] = __builtin_amdgcn_mfma_f32_16x16x32_bf16(ah0, bl, acc[0][t_], 0, 0, 0); \
            acc[1][t_] = __builtin_amdgcn_mfma_f32_16x16x32_bf16(ah1, bl, acc[1][t_], 0, 0, 0); \
            acc[0][t_] = __builtin_amdgcn_mfma_f32_16x16x32_bf16(al0, bh, acc[0][t_], 0, 0, 0); \
            acc[1][t_] = __builtin_amdgcn_mfma_f32_16x16x32_bf16(al1, bh, acc[1][t_], 0, 0, 0); \
        }                                                                       \
    }                                                                           \
} while (0)

// Half-strip store of pair p's acc: half 0 from lanes r0w<8 (strip rows 0-7),
// half 1 from lanes r0w>=8 (rows 8-15); both land on buffer rows 0..7.
// (R5-verified scheme; preceded by lds_fence.)
#define STORE_H(p, half, buf) do {                             \
    if ((r0w & 8) == ((half) << 3)) {                          \
        float* pb = (buf) + (r0w & 7) * CSTR + c0w;            \
        _Pragma("unroll")                                      \
        for (int t_ = 0; t_ < 8; ++t_) {                       \
            float* q = pb + (t_ << 4);                         \
            q[0]        = acc[p][t_][0];                       \
            q[CSTR]     = acc[p][t_][1];                       \
            q[2 * CSTR] = acc[p][t_][2];                       \
            q[3 * CSTR] = acc[p][t_][3];                       \
        }                                                      \
    }                                                          \
} while (0)

#define LOAD_A_N(poff) do {                                    \
    int off = (poff) + lane;                                   \
    N0h[0] = Ahg0[off]; N0h[1] = Ahg0[off + 64];               \
    N0l[0] = Alg0[off]; N0l[1] = Alg0[off + 64];               \
    N1h[0] = Ahg1[off]; N1h[1] = Ahg1[off + 64];               \
    N1l[0] = Alg1[off]; N1l[1] = Alg1[off + 64];               \
} while (0)

    // prologue: strip 0 fragments + MFMAs
    {
        int off = lane;
        A0h[0] = Ahg0[off]; A0h[1] = Ahg0[off + 64];
        A0l[0] = Alg0[off]; A0l[1] = Alg0[off + 64];
        A1h[0] = Ahg1[off]; A1h[1] = Ahg1[off + 64];
        A1l[0] = Alg1[off]; A1l[1] = Alg1[off + 64];
    }
    MFMA_PASS();                             // acc = inc strip 0, both pairs

    for (int s = 0; s < 8; ++s) {
        if (s < 7) LOAD_A_N((s + 1) * 128);  // global prefetch, consumed below

        // ---- half A: strip rows 0-7, both pairs, one chain pass ---------
        float4 svA[8];
        lds_fence();                          // prev svB consumed -> ~free
        STORE_H(0, 0, buf0);
        STORE_H(1, 0, buf1);
        load4<8>(myBuf, c4, svA);
        chain4<8>(svA, lq0, lq31, Sv, e0p, e1p, e2p, e3p);

        // ---- half B: strip rows 8-15 ------------------------------------
        lds_fence();                          // svA consumed by chain -> free
        STORE_H(0, 1, buf0);
        STORE_H(1, 1, buf1);
        if (s < 7) {
            float4 svB[8];
            load4<8>(myBuf, c4, svB);
            A0h[0] = N0h[0]; A0h[1] = N0h[1]; A0l[0] = N0l[0]; A0l[1] = N0l[1];
            A1h[0] = N1h[0]; A1h[1] = N1h[1]; A1l[0] = N1l[0]; A1l[1] = N1l[1];
            MFMA_PASS();                      // next strip; hides under chain
            chain4<8>(svB, lq0, lq31, Sv, e0p, e1p, e2p, e3p);
        } else {
            float4 svB[7];                    // last strip: rows 120..126
            load4<7>(myBuf, c4, svB);
            chain4<7>(svB, lq0, lq31, Sv, e0p, e1p, e2p, e3p);
        }
    }

    if (lq == 31) {                           // lane 31: pair0, lane 63: pair1
        float wgt = (lane < 32) ? wgt0 : wgt1;
        red8[2 * w + (lane >> 5)] = wgt * (1.0f + Sv - e3p);
    }
    __syncthreads();
    if (tid == 0) {
        float r = 0.f;
        #pragma unroll
        for (int i = 0; i < 8; ++i) r += red8[i];
        partials[gid] = r;
    }

#undef MFMA_PASS
#undef STORE_H
#undef LOAD_A_N
}

// ---------------------------------------------------------------------------
// final: out[0] = sum(partials) + mean((X0-Y0)^2).
// ---------------------------------------------------------------------------
__global__ void final_sum(const float* __restrict__ X, const float* __restrict__ Y,
                          const float* __restrict__ partials, float* __restrict__ out) {
    __shared__ float red[4];
    int tid = threadIdx.x;                   // 256 threads
    float acc = 0.f;
    for (int e = tid; e < NBLK; e += 256) acc += partials[e];
    for (int e = tid; e < AA * DD; e += 256) {
        int aa = e >> 6, d = e & 63;
        float df = X[aa * (MM * DD) + d] - Y[aa * (MM * DD) + d];
        acc = fmaf(df * df, 1.0f / 4096.0f, acc);
    }
    #pragma unroll
    for (int off = 32; off > 0; off >>= 1) acc += __shfl_down(acc, off);
    if ((tid & 63) == 0) red[tid >> 6] = acc;
    __syncthreads();
    if (tid == 0) out[0] = red[0] + red[1] + red[2] + red[3];
}

extern "C" void kernel_launch(void* const* d_in, const int* in_sizes, int n_in,
                              void* d_out, int out_size, void* d_ws, size_t ws_size,
                              hipStream_t stream) {
    const float* X = (const float*)d_in[0];
    const float* Y = (const float*)d_in[1];
    float* out = (float*)d_out;
    int4*  frag = (int4*)d_ws;
    float* partials = (float*)((char*)d_ws + PART_OFF);

    hipLaunchKernelGGL(prep_frags, dim3(256), dim3(256), 0, stream, X, Y, frag);
    hipLaunchKernelGGL(sig_pde, dim3(NBLK), dim3(256), 0, stream, frag, partials);
    hipLaunchKernelGGL(final_sum, dim3(1), dim3(256), 0, stream, X, Y, partials, out);
}